// Round 10
// baseline (2263.042 us; speedup 1.0000x reference)
//
#include <hip/hip_runtime.h>
#include <hip/hip_bf16.h>
#include <math.h>

#define NNODES 100000
#define NREL 4
#define NEDGE 200000
#define NH 8
#define FDIM 512
#define NMB256 391  // ceil(100000/256)

typedef float f4 __attribute__((ext_vector_type(4)));
typedef __bf16 bf16x8 __attribute__((ext_vector_type(8)));
typedef __bf16 bf16x4 __attribute__((ext_vector_type(4)));

__device__ __forceinline__ float eluf(float v) { return v > 0.f ? v : expm1f(v); }
__device__ __forceinline__ void gload16(const __bf16* g, __bf16* l) {
  __builtin_amdgcn_global_load_lds((const __attribute__((address_space(1))) void*)g,
                                   (__attribute__((address_space(3))) void*)l, 16, 0, 0);
}

// ---- f32 -> bf16 convert (count multiple of 1024) ----
__global__ void k_conv(const float* __restrict__ in, __bf16* __restrict__ outp) {
  int i = (blockIdx.x * 256 + threadIdx.x) * 4;
  f4 v = *(const f4*)(in + i);
  bf16x4 o = {(__bf16)v.x, (__bf16)v.y, (__bf16)v.z, (__bf16)v.w};
  *(bf16x4*)(outp + i) = o;
}

// ---- W [R,K,512] f32 -> Wt [R*512, K] bf16 (transposed) ----
__global__ void k_transW(const float* __restrict__ W, __bf16* __restrict__ Wt, int K) {
  __shared__ float tile[32][33];
  int r = blockIdx.z;
  const float* Wr = W + (size_t)r * K * FDIM;
  __bf16* Wtr = Wt + (size_t)r * FDIM * K;
  int k0 = blockIdx.x * 32, n0 = blockIdx.y * 32;
  int tx = threadIdx.x, ty = threadIdx.y;
  for (int i = ty; i < 32; i += 8)
    tile[i][tx] = Wr[(size_t)(k0 + i) * FDIM + n0 + tx];
  __syncthreads();
  for (int i = ty; i < 32; i += 8)
    Wtr[(size_t)(n0 + i) * K + k0 + tx] = (__bf16)tile[tx][i];
}

// ---- bf16 MFMA GEMM: 256x256 tile, 8 waves, BK=32, 3-buffer phase-split pipeline,
//      counted vmcnt(4), raw barriers + setprio, fused el/er epilogue. C[M,512] ----
__global__ __launch_bounds__(512, 2) void k_gemm(const __bf16* __restrict__ A,
                                                 const __bf16* __restrict__ BT,
                                                 __bf16* __restrict__ C,
                                                 const float* __restrict__ al,
                                                 const float* __restrict__ ar,
                                                 __bf16* __restrict__ el,
                                                 __bf16* __restrict__ er, int M, int K) {
  // 3 bufs x 4 regions (A-half0, A-half1, B-half0, B-half1), each [128][32] bf16 = 8KB -> 96KB
  __shared__ alignas(16) __bf16 lds[3][4][128 * 32];
  int t = threadIdx.x, l = t & 63, w = t >> 6;  // 8 waves
  // bijective XCD-chunked swizzle (m204)
  int nwg = gridDim.x, q8 = nwg >> 3, r8 = nwg & 7;
  int xx = blockIdx.x & 7, loc = blockIdx.x >> 3;
  int swz = (xx < r8 ? xx * (q8 + 1) : r8 * (q8 + 1) + (xx - r8) * q8) + loc;
  int m0 = (swz >> 1) * 256, n0 = (swz & 1) * 256;
  int wm = (w >> 2) * 128, wn = (w & 3) * 64;  // wave -> 128x64 output
  f4 acc[8][4] = {};

  // staging: thread t loads one 16B chunk per region per tile (linear LDS dest,
  // pre-swizzled global source col: chunk (t&3) ^ (row&3))
  int srow = t >> 2;                      // 0..127
  int scol = ((t & 3) ^ (srow & 3)) * 8;  // elems
  const __bf16* pS[4];
  {
    int ra0 = m0 + srow;       if (ra0 >= M) ra0 = M - 1;
    int ra1 = m0 + 128 + srow; if (ra1 >= M) ra1 = M - 1;
    pS[0] = A + (size_t)ra0 * K + scol;
    pS[1] = A + (size_t)ra1 * K + scol;
    pS[2] = BT + (size_t)(n0 + srow) * K + scol;
    pS[3] = BT + (size_t)(n0 + 128 + srow) * K + scol;
  }
#define STG(tile, rgn) gload16(pS[rgn] + (size_t)(tile) * 32, &lds[(tile) % 3][rgn][t * 8])

  // reader: swizzled K-slot, per-lane constant
  int roff = ((l >> 4) ^ (l & 3)) * 8;
  int areg = w >> 2;              // A region 0/1
  int breg = 2 + ((w & 3) >> 1);  // B region 2/3
  int brow0 = (w & 1) * 64;       // B row base within region

  int nt = K >> 5;  // 8 or 16
  // prologue: stage tiles 0,1
#pragma unroll
  for (int g = 0; g < 4; g++) STG(0, g);
#pragma unroll
  for (int g = 0; g < 4; g++) STG(1, g);
  asm volatile("s_waitcnt vmcnt(4)" :::);  // tile0 landed (tile1 in flight)
  __builtin_amdgcn_s_barrier();
  __builtin_amdgcn_sched_barrier(0);

  for (int k = 0; k < nt; k++) {
    int bk = k % 3;
    bool stg = (k + 2) < nt;
    bf16x8 b[4], af[4];
    // ---------- phase 0: M-half 0 ----------
#pragma unroll
    for (int j = 0; j < 4; j++)
      b[j] = *(const bf16x8*)(&lds[bk][breg][(brow0 + j * 16 + (l & 15)) * 32 + roff]);
#pragma unroll
    for (int i = 0; i < 4; i++)
      af[i] = *(const bf16x8*)(&lds[bk][areg][(i * 16 + (l & 15)) * 32 + roff]);
    if (stg) { STG(k + 2, 0); STG(k + 2, 1); }
    __builtin_amdgcn_s_barrier();
    asm volatile("s_waitcnt lgkmcnt(0)" ::: "memory");
    __builtin_amdgcn_sched_barrier(0);
    __builtin_amdgcn_s_setprio(1);
#pragma unroll
    for (int i = 0; i < 4; i++)
#pragma unroll
      for (int j = 0; j < 4; j++)
        acc[i][j] = __builtin_amdgcn_mfma_f32_16x16x32_bf16(af[i], b[j], acc[i][j], 0, 0, 0);
    __builtin_amdgcn_s_setprio(0);
    __builtin_amdgcn_s_barrier();
    __builtin_amdgcn_sched_barrier(0);
    // ---------- phase 1: M-half 1 ----------
#pragma unroll
    for (int i = 0; i < 4; i++)
      af[i] = *(const bf16x8*)(&lds[bk][areg][(64 + i * 16 + (l & 15)) * 32 + roff]);
    if (stg) { STG(k + 2, 2); STG(k + 2, 3); }
    if (k + 2 < nt)      asm volatile("s_waitcnt vmcnt(4)" :::);  // T_{k+1} landed
    else if (k + 1 < nt) asm volatile("s_waitcnt vmcnt(0)" :::);  // drain for last tile
    __builtin_amdgcn_s_barrier();
    asm volatile("s_waitcnt lgkmcnt(0)" ::: "memory");
    __builtin_amdgcn_sched_barrier(0);
    __builtin_amdgcn_s_setprio(1);
#pragma unroll
    for (int i = 0; i < 4; i++)
#pragma unroll
      for (int j = 0; j < 4; j++)
        acc[4 + i][j] = __builtin_amdgcn_mfma_f32_16x16x32_bf16(af[i], b[j], acc[4 + i][j], 0, 0, 0);
    __builtin_amdgcn_s_setprio(0);
    __builtin_amdgcn_s_barrier();
    __builtin_amdgcn_sched_barrier(0);
  }
#undef STG

  // ---- C write (bf16, scalar stores — proven pattern) ----
  int cn = n0 + wn + (l & 15);
  int rbase = m0 + wm + (l >> 4) * 4;
#pragma unroll
  for (int i = 0; i < 8; i++)
#pragma unroll
    for (int q2 = 0; q2 < 4; q2++) {
      int row = rbase + i * 16 + q2;
      if (row < M) {
#pragma unroll
        for (int j = 0; j < 4; j++)
          C[(size_t)row * FDIM + cn + j * 16] = (__bf16)acc[i][j][q2];
      }
    }

  // ---- fused el/er (bf16 out): wave's 64-col slice == one head ----
  int h = (n0 + wn) >> 6;
  float av[4], bv[4];
#pragma unroll
  for (int j = 0; j < 4; j++) {
    av[j] = al[h * 64 + j * 16 + (l & 15)];
    bv[j] = ar[h * 64 + j * 16 + (l & 15)];
  }
#pragma unroll
  for (int i = 0; i < 8; i++)
#pragma unroll
    for (int q2 = 0; q2 < 4; q2++) {
      float se = acc[i][0][q2] * av[0] + acc[i][1][q2] * av[1] +
                 acc[i][2][q2] * av[2] + acc[i][3][q2] * av[3];
      float sr = acc[i][0][q2] * bv[0] + acc[i][1][q2] * bv[1] +
                 acc[i][2][q2] * bv[2] + acc[i][3][q2] * bv[3];
      se += __shfl_xor(se, 1); se += __shfl_xor(se, 2);
      se += __shfl_xor(se, 4); se += __shfl_xor(se, 8);
      sr += __shfl_xor(sr, 1); sr += __shfl_xor(sr, 2);
      sr += __shfl_xor(sr, 4); sr += __shfl_xor(sr, 8);
      if ((l & 15) == 0) {
        int row = rbase + i * 16 + q2;
        if (row < M) {
          el[row * NH + h] = (__bf16)se;
          er[row * NH + h] = (__bf16)sr;
        }
      }
    }
}

// ---- CSR build ----
__global__ void k_count(const int* __restrict__ dst, int* __restrict__ deg) {
  int e = blockIdx.x * 256 + threadIdx.x;
  int r = blockIdx.y;
  if (e < NEDGE) {
    int d = dst[(size_t)r * NEDGE + e];
    if ((unsigned)d < (unsigned)NNODES) atomicAdd(&deg[r * NNODES + d], 1);
  }
}

__global__ __launch_bounds__(256) void k_scan_a(const int* __restrict__ in, int* __restrict__ out,
                                                int* __restrict__ bsum, int n) {
  __shared__ int wsums[4];
  int t = threadIdx.x, lane = t & 63, w = t >> 6;
  int base = blockIdx.x * 1024 + t * 4;
  int v0 = base + 0 < n ? in[base + 0] : 0;
  int v1 = base + 1 < n ? in[base + 1] : 0;
  int v2 = base + 2 < n ? in[base + 2] : 0;
  int v3 = base + 3 < n ? in[base + 3] : 0;
  int tot = v0 + v1 + v2 + v3;
  int sc = tot;
#pragma unroll
  for (int off = 1; off < 64; off <<= 1) {
    int u = __shfl_up(sc, off);
    if (lane >= off) sc += u;
  }
  if (lane == 63) wsums[w] = sc;
  __syncthreads();
  int add = 0;
#pragma unroll
  for (int i = 0; i < 4; i++)
    if (i < w) add += wsums[i];
  int excl = add + sc - tot;
  if (base + 0 < n) out[base + 0] = excl;
  if (base + 1 < n) out[base + 1] = excl + v0;
  if (base + 2 < n) out[base + 2] = excl + v0 + v1;
  if (base + 3 < n) out[base + 3] = excl + v0 + v1 + v2;
  if (t == 255) bsum[blockIdx.x] = add + sc;
}

__global__ __launch_bounds__(256) void k_scan_b(int* __restrict__ bsum, int nb) {
  __shared__ int wsums[4];
  int t = threadIdx.x, lane = t & 63, w = t >> 6;
  int i0 = t * 2, i1 = t * 2 + 1;
  int v0 = i0 < nb ? bsum[i0] : 0;
  int v1 = i1 < nb ? bsum[i1] : 0;
  int tot = v0 + v1, sc = tot;
#pragma unroll
  for (int off = 1; off < 64; off <<= 1) {
    int u = __shfl_up(sc, off);
    if (lane >= off) sc += u;
  }
  if (lane == 63) wsums[w] = sc;
  __syncthreads();
  int add = 0;
#pragma unroll
  for (int i = 0; i < 4; i++)
    if (i < w) add += wsums[i];
  int excl = add + sc - tot;
  if (i0 < nb) bsum[i0] = excl;
  if (i1 < nb) bsum[i1] = excl + v0;
}

__global__ void k_scan_c(int* __restrict__ out, const int* __restrict__ bsum, int n) {
  int i = blockIdx.x * 256 + threadIdx.x;
  if (i < n) out[i] += bsum[i >> 10];
}

__global__ void k_scatter(const int* __restrict__ src, const int* __restrict__ dst,
                          const int* __restrict__ ptrf, int* __restrict__ cur,
                          int* __restrict__ csrc) {
  int e = blockIdx.x * 256 + threadIdx.x;
  int r = blockIdx.y;
  if (e >= NEDGE) return;
  int d = dst[(size_t)r * NEDGE + e];
  if ((unsigned)d >= (unsigned)NNODES) return;
  int slot = ptrf[r * NNODES + d] + atomicAdd(&cur[r * NNODES + d], 1);
  if ((unsigned)slot < (unsigned)(NREL * NEDGE))
    csrc[slot] = src[(size_t)r * NEDGE + e];
}

// ---- fused segment-softmax + aggregate + ELU; writeMode=1: full write (replaces memset) ----
__global__ void k_agg(const __bf16* __restrict__ f, const __bf16* __restrict__ el,
                      const __bf16* __restrict__ er, const int* __restrict__ ptrf,
                      const int* __restrict__ deg, const int* __restrict__ csrc,
                      __bf16* __restrict__ accG, int writeMode) {
  int t = threadIdx.x;
  int l = t & 63;
  int d = blockIdx.x * 4 + (t >> 6);
  int h = l >> 3;
  int cnt = deg[d];
  float res[8] = {0.f, 0.f, 0.f, 0.f, 0.f, 0.f, 0.f, 0.f};
  if (cnt > 0) {
    int start = ptrf[d];
    if (start < 0) start = 0;
    if (start > NREL * NEDGE) start = NREL * NEDGE;
    if (cnt > NREL * NEDGE - start) cnt = NREL * NEDGE - start;
    float erh = (float)er[d * NH + h];
    float a[8] = {0.f, 0.f, 0.f, 0.f, 0.f, 0.f, 0.f, 0.f};
    float den = 0.f;
    for (int j = 0; j < cnt; j++) {
      int s = csrc[start + j];
      if ((unsigned)s >= (unsigned)NNODES) s = 0;
      float e = (float)el[s * NH + h] + erh;
      e = (e > 0.f) ? e : 0.2f * e;
      float ex = __expf(e);
      den += ex;
      bf16x8 fv = *(const bf16x8*)(f + (size_t)s * FDIM + l * 8);
#pragma unroll
      for (int i = 0; i < 8; i++) a[i] += ex * (float)fv[i];
    }
    float inv = 1.f / (den + 1e-9f);
#pragma unroll
    for (int i = 0; i < 8; i++) res[i] = eluf(a[i] * inv);
  } else if (!writeMode) {
    return;
  }
  __bf16* ap = accG + (size_t)d * FDIM + l * 8;
  bf16x8 o;
  if (writeMode) {
#pragma unroll
    for (int i = 0; i < 8; i++) o[i] = (__bf16)res[i];
  } else {
    bf16x8 cv = *(bf16x8*)ap;
#pragma unroll
    for (int i = 0; i < 8; i++) o[i] = (__bf16)((float)cv[i] + res[i]);
  }
  *(bf16x8*)ap = o;
}

// ---- final mean over heads ----
__global__ void k_mean(const __bf16* __restrict__ acc, float* __restrict__ out) {
  int t = blockIdx.x * 256 + threadIdx.x;
  int n = t >> 6, o = t & 63;
  const __bf16* ap = acc + (size_t)n * FDIM + o;
  float s = 0.f;
#pragma unroll
  for (int h = 0; h < 8; h++) s += (float)ap[h * 64];
  out[t] = s * 0.125f;
}

// ---- host ----
extern "C" void kernel_launch(void* const* d_in, const int* in_sizes, int n_in,
                              void* d_out, int out_size, void* d_ws, size_t ws_size,
                              hipStream_t stream) {
  const float* x = (const float*)d_in[0];
  const int* srcp = (const int*)d_in[1];
  const int* dstp = (const int*)d_in[2];
  const float* Wl[3]  = {(const float*)d_in[3], (const float*)d_in[6], (const float*)d_in[9]};
  const float* alp[3] = {(const float*)d_in[4], (const float*)d_in[7], (const float*)d_in[10]};
  const float* arl[3] = {(const float*)d_in[5], (const float*)d_in[8], (const float*)d_in[11]};
  float* out = (float*)d_out;
  (void)in_sizes; (void)n_in; (void)out_size;

  auto rup = [](size_t b) { return (b + 255) & ~(size_t)255; };
  size_t need = 3 * rup((size_t)NNODES * FDIM * 2) +        // bufA, bufB, fbuf
                2 * rup((size_t)NNODES * NH * 2) +          // el, er (bf16)
                rup((size_t)NREL * FDIM * FDIM * 2) +       // Wt
                3 * rup((size_t)NREL * NNODES * 4) +        // deg, ptrf, cur
                rup((size_t)NREL * NEDGE * 4) + rup(4096);
  if (ws_size < need) return;

  char* ws = (char*)d_ws;
  size_t off = 0;
  auto alloc = [&](size_t bytes) -> void* { void* p = ws + off; off += rup(bytes); return p; };
  __bf16* bufA = (__bf16*)alloc((size_t)NNODES * FDIM * 2);
  __bf16* bufB = (__bf16*)alloc((size_t)NNODES * FDIM * 2);
  __bf16* fbuf = (__bf16*)alloc((size_t)NNODES * FDIM * 2);
  __bf16* el   = (__bf16*)alloc((size_t)NNODES * NH * 2);
  __bf16* er   = (__bf16*)alloc((size_t)NNODES * NH * 2);
  __bf16* Wt   = (__bf16*)alloc((size_t)NREL * FDIM * FDIM * 2);
  int* deg  = (int*)alloc((size_t)NREL * NNODES * 4);
  int* ptrf = (int*)alloc((size_t)NREL * NNODES * 4);
  int* cur  = (int*)alloc((size_t)NREL * NNODES * 4);
  int* csrc = (int*)alloc((size_t)NREL * NEDGE * 4);
  int* bsum = (int*)alloc(4096);

  // ---- CSR by dst ----
  hipMemsetAsync(deg, 0, (size_t)NREL * NNODES * 4, stream);
  hipMemsetAsync(cur, 0, (size_t)NREL * NNODES * 4, stream);
  k_count<<<dim3((NEDGE + 255) / 256, NREL), 256, 0, stream>>>(dstp, deg);
  int ntot = NREL * NNODES;
  int nb1 = (ntot + 1023) / 1024;
  k_scan_a<<<nb1, 256, 0, stream>>>(deg, ptrf, bsum, ntot);
  k_scan_b<<<1, 256, 0, stream>>>(bsum, nb1);
  k_scan_c<<<(ntot + 255) / 256, 256, 0, stream>>>(ptrf, bsum, ntot);
  k_scatter<<<dim3((NEDGE + 255) / 256, NREL), 256, 0, stream>>>(srcp, dstp, ptrf, cur, csrc);

  k_conv<<<(NNODES * 256) / 1024, 256, 0, stream>>>(x, bufA);

  __bf16* inb = bufA;
  __bf16* outb = bufB;
  int ngrid = NMB256 * 2;  // 782
  for (int L = 0; L < 3; L++) {
    int K = (L == 0) ? 256 : FDIM;
    k_transW<<<dim3(K / 32, 16, NREL), dim3(32, 8), 0, stream>>>(Wl[L], Wt, K);
    for (int r = 0; r < NREL; r++) {
      k_gemm<<<ngrid, 512, 0, stream>>>(inb, Wt + (size_t)r * FDIM * K, fbuf,
                                        alp[L] + (size_t)r * 512,
                                        arl[L] + (size_t)r * 512,
                                        el, er, NNODES, K);
      k_agg<<<NNODES / 4, 256, 0, stream>>>(fbuf, el, er, ptrf + (size_t)r * NNODES,
                                            deg + (size_t)r * NNODES, csrc, outb,
                                            r == 0 ? 1 : 0);
    }
    __bf16* tmp = inb; inb = outb; outb = tmp;
  }
  k_mean<<<(NNODES * 64) / 256, 256, 0, stream>>>(inb, out);
}

// Round 11
// 2042.556 us; speedup vs baseline: 1.1079x; 1.1079x over previous
//
#include <hip/hip_runtime.h>
#include <hip/hip_bf16.h>
#include <math.h>

#define NNODES 100000
#define NREL 4
#define NEDGE 200000
#define NH 8
#define FDIM 512
#define NMB 782  // ceil(100000/128)

typedef float f4 __attribute__((ext_vector_type(4)));
typedef __bf16 bf16x8 __attribute__((ext_vector_type(8)));
typedef __bf16 bf16x4 __attribute__((ext_vector_type(4)));

__device__ __forceinline__ float eluf(float v) { return v > 0.f ? v : expm1f(v); }
__device__ __forceinline__ void gload16(const __bf16* g, __bf16* l) {
  __builtin_amdgcn_global_load_lds((const __attribute__((address_space(1))) void*)g,
                                   (__attribute__((address_space(3))) void*)l, 16, 0, 0);
}

// ---- f32 -> bf16 convert (count multiple of 1024) ----
__global__ void k_conv(const float* __restrict__ in, __bf16* __restrict__ outp) {
  int i = (blockIdx.x * 256 + threadIdx.x) * 4;
  f4 v = *(const f4*)(in + i);
  bf16x4 o = {(__bf16)v.x, (__bf16)v.y, (__bf16)v.z, (__bf16)v.w};
  *(bf16x4*)(outp + i) = o;
}

// ---- W [z,K,512] f32 -> Wt [z*512, K] bf16 (transposed); z relations per call ----
__global__ void k_transW(const float* __restrict__ W, __bf16* __restrict__ Wt, int K) {
  __shared__ float tile[32][33];
  int r = blockIdx.z;
  const float* Wr = W + (size_t)r * K * FDIM;
  __bf16* Wtr = Wt + (size_t)r * FDIM * K;
  int k0 = blockIdx.x * 32, n0 = blockIdx.y * 32;
  int tx = threadIdx.x, ty = threadIdx.y;
  for (int i = ty; i < 32; i += 8)
    tile[i][tx] = Wr[(size_t)(k0 + i) * FDIM + n0 + tx];
  __syncthreads();
  for (int i = ty; i < 32; i += 8)
    Wtr[(size_t)(n0 + i) * K + k0 + tx] = (__bf16)tile[tx][i];
}

// ---- bf16 MFMA GEMM (R9-proven): 128x256 tile, 2-buffer counted-vmcnt, bijective
//      XCD swizzle, fused el/er epilogue (bf16). C[M, 256<<nnbsh] = A[M,K]*BT^T ----
__global__ __launch_bounds__(256, 2) void k_gemm(const __bf16* __restrict__ A,
                                                 const __bf16* __restrict__ BT,
                                                 __bf16* __restrict__ C,
                                                 const float* __restrict__ al,
                                                 const float* __restrict__ ar,
                                                 __bf16* __restrict__ el,
                                                 __bf16* __restrict__ er, int M, int K,
                                                 int nnbsh) {
  __shared__ alignas(16) __bf16 lA[2][128 * 32];
  __shared__ alignas(16) __bf16 lB[2][256 * 32];
  int t = threadIdx.x, l = t & 63, w = t >> 6;
  int nwg = gridDim.x, q8 = nwg >> 3, r8 = nwg & 7;
  int xx = blockIdx.x & 7, loc = blockIdx.x >> 3;
  int swz = (xx < r8 ? xx * (q8 + 1) : r8 * (q8 + 1) + (xx - r8) * q8) + loc;
  int nnbm = (1 << nnbsh) - 1;
  int m0 = (swz >> nnbsh) * 128, n0 = (swz & nnbm) * 256;
  int NDIM = 256 << nnbsh;
  int nh_tot = 4 << nnbsh;
  int wm = (w >> 1) * 64, wn = (w & 1) * 128;
  f4 acc[4][8] = {};

  const __bf16* pA[2];
  const __bf16* pB[4];
#pragma unroll
  for (int u = 0; u < 2; u++) {
    int s = t + u * 256;
    int row = m0 + (s >> 2); if (row >= M) row = M - 1;
    pA[u] = A + (size_t)row * K + (((s & 3) ^ ((s >> 2) & 3)) * 8);
  }
#pragma unroll
  for (int u = 0; u < 4; u++) {
    int s = t + u * 256;
    pB[u] = BT + (size_t)(n0 + (s >> 2)) * K + (((s & 3) ^ ((s >> 2) & 3)) * 8);
  }

#define STAGE(buf, kk)                                      \
  do {                                                      \
    gload16(pA[0] + (kk), &lA[buf][t * 8]);                 \
    gload16(pA[1] + (kk), &lA[buf][(t + 256) * 8]);         \
    gload16(pB[0] + (kk), &lB[buf][t * 8]);                 \
    gload16(pB[1] + (kk), &lB[buf][(t + 256) * 8]);         \
    gload16(pB[2] + (kk), &lB[buf][(t + 512) * 8]);         \
    gload16(pB[3] + (kk), &lB[buf][(t + 768) * 8]);         \
  } while (0)

  int nt = K >> 5;
  STAGE(0, 0);
  STAGE(1, 32);
  int segoff = ((l >> 4) ^ (l & 3)) * 8;
  int rofA = (wm + (l & 15)) * 32 + segoff;
  int rofB = (wn + (l & 15)) * 32 + segoff;
  for (int kt = 0; kt < nt; kt++) {
    int cur = kt & 1;
    if (kt + 1 < nt) asm volatile("s_waitcnt vmcnt(6)" ::: "memory");
    else             asm volatile("s_waitcnt vmcnt(0)" ::: "memory");
    __builtin_amdgcn_s_barrier();
    bf16x8 a[4], b[8];
#pragma unroll
    for (int i = 0; i < 4; i++) a[i] = *(const bf16x8*)(&lA[cur][rofA + i * 512]);
#pragma unroll
    for (int j = 0; j < 8; j++) b[j] = *(const bf16x8*)(&lB[cur][rofB + j * 512]);
    asm volatile("s_waitcnt lgkmcnt(0)" ::: "memory");
    __builtin_amdgcn_s_barrier();
    if (kt + 2 < nt) STAGE(cur, (kt + 2) * 32);
#pragma unroll
    for (int i = 0; i < 4; i++)
#pragma unroll
      for (int j = 0; j < 8; j++)
        acc[i][j] = __builtin_amdgcn_mfma_f32_16x16x32_bf16(a[i], b[j], acc[i][j], 0, 0, 0);
  }
#undef STAGE

  int cn = n0 + wn + (l & 15);
  int rbase = m0 + wm + (l >> 4) * 4;
#pragma unroll
  for (int i = 0; i < 4; i++)
#pragma unroll
    for (int q2 = 0; q2 < 4; q2++) {
      int row = rbase + i * 16 + q2;
      if (row < M) {
#pragma unroll
        for (int j = 0; j < 8; j++)
          C[(size_t)row * NDIM + cn + j * 16] = (__bf16)acc[i][j][q2];
      }
    }

  int hbase = (n0 + wn) >> 6;
  float av[8], bv[8];
#pragma unroll
  for (int j = 0; j < 8; j++) {
    int h = hbase + (j >> 2);
    av[j] = al[h * 64 + (j & 3) * 16 + (l & 15)];
    bv[j] = ar[h * 64 + (j & 3) * 16 + (l & 15)];
  }
#pragma unroll
  for (int i = 0; i < 4; i++)
#pragma unroll
    for (int q2 = 0; q2 < 4; q2++) {
#pragma unroll
      for (int half = 0; half < 2; half++) {
        float se = acc[i][half * 4 + 0][q2] * av[half * 4 + 0] +
                   acc[i][half * 4 + 1][q2] * av[half * 4 + 1] +
                   acc[i][half * 4 + 2][q2] * av[half * 4 + 2] +
                   acc[i][half * 4 + 3][q2] * av[half * 4 + 3];
        float sr = acc[i][half * 4 + 0][q2] * bv[half * 4 + 0] +
                   acc[i][half * 4 + 1][q2] * bv[half * 4 + 1] +
                   acc[i][half * 4 + 2][q2] * bv[half * 4 + 2] +
                   acc[i][half * 4 + 3][q2] * bv[half * 4 + 3];
        se += __shfl_xor(se, 1); se += __shfl_xor(se, 2);
        se += __shfl_xor(se, 4); se += __shfl_xor(se, 8);
        sr += __shfl_xor(sr, 1); sr += __shfl_xor(sr, 2);
        sr += __shfl_xor(sr, 4); sr += __shfl_xor(sr, 8);
        if ((l & 15) == 0) {
          int row = rbase + i * 16 + q2;
          if (row < M) {
            int h = hbase + half;
            el[row * nh_tot + h] = (__bf16)se;
            er[row * nh_tot + h] = (__bf16)sr;
          }
        }
      }
    }
}

// ---- CSR build ----
__global__ void k_count(const int* __restrict__ dst, int* __restrict__ deg) {
  int e = blockIdx.x * 256 + threadIdx.x;
  int r = blockIdx.y;
  if (e < NEDGE) {
    int d = dst[(size_t)r * NEDGE + e];
    if ((unsigned)d < (unsigned)NNODES) atomicAdd(&deg[r * NNODES + d], 1);
  }
}

__global__ __launch_bounds__(256) void k_scan_a(const int* __restrict__ in, int* __restrict__ out,
                                                int* __restrict__ bsum, int n) {
  __shared__ int wsums[4];
  int t = threadIdx.x, lane = t & 63, w = t >> 6;
  int base = blockIdx.x * 1024 + t * 4;
  int v0 = base + 0 < n ? in[base + 0] : 0;
  int v1 = base + 1 < n ? in[base + 1] : 0;
  int v2 = base + 2 < n ? in[base + 2] : 0;
  int v3 = base + 3 < n ? in[base + 3] : 0;
  int tot = v0 + v1 + v2 + v3;
  int sc = tot;
#pragma unroll
  for (int off = 1; off < 64; off <<= 1) {
    int u = __shfl_up(sc, off);
    if (lane >= off) sc += u;
  }
  if (lane == 63) wsums[w] = sc;
  __syncthreads();
  int add = 0;
#pragma unroll
  for (int i = 0; i < 4; i++)
    if (i < w) add += wsums[i];
  int excl = add + sc - tot;
  if (base + 0 < n) out[base + 0] = excl;
  if (base + 1 < n) out[base + 1] = excl + v0;
  if (base + 2 < n) out[base + 2] = excl + v0 + v1;
  if (base + 3 < n) out[base + 3] = excl + v0 + v1 + v2;
  if (t == 255) bsum[blockIdx.x] = add + sc;
}

__global__ __launch_bounds__(256) void k_scan_b(int* __restrict__ bsum, int nb) {
  __shared__ int wsums[4];
  int t = threadIdx.x, lane = t & 63, w = t >> 6;
  int i0 = t * 2, i1 = t * 2 + 1;
  int v0 = i0 < nb ? bsum[i0] : 0;
  int v1 = i1 < nb ? bsum[i1] : 0;
  int tot = v0 + v1, sc = tot;
#pragma unroll
  for (int off = 1; off < 64; off <<= 1) {
    int u = __shfl_up(sc, off);
    if (lane >= off) sc += u;
  }
  if (lane == 63) wsums[w] = sc;
  __syncthreads();
  int add = 0;
#pragma unroll
  for (int i = 0; i < 4; i++)
    if (i < w) add += wsums[i];
  int excl = add + sc - tot;
  if (i0 < nb) bsum[i0] = excl;
  if (i1 < nb) bsum[i1] = excl + v0;
}

__global__ void k_scan_c(int* __restrict__ out, const int* __restrict__ bsum, int n) {
  int i = blockIdx.x * 256 + threadIdx.x;
  if (i < n) out[i] += bsum[i >> 10];
}

__global__ void k_scatter(const int* __restrict__ src, const int* __restrict__ dst,
                          const int* __restrict__ ptrf, int* __restrict__ cur,
                          int* __restrict__ csrc) {
  int e = blockIdx.x * 256 + threadIdx.x;
  int r = blockIdx.y;
  if (e >= NEDGE) return;
  int d = dst[(size_t)r * NEDGE + e];
  if ((unsigned)d >= (unsigned)NNODES) return;
  int slot = ptrf[r * NNODES + d] + atomicAdd(&cur[r * NNODES + d], 1);
  if ((unsigned)slot < (unsigned)(NREL * NEDGE))
    csrc[slot] = src[(size_t)r * NEDGE + e];
}

// ---- fused segment-softmax + aggregate + ELU, nrr relations/pass; writeMode: full write ----
__global__ void k_agg(const __bf16* __restrict__ f, const __bf16* __restrict__ el,
                      const __bf16* __restrict__ er, const int* __restrict__ ptrf,
                      const int* __restrict__ deg, const int* __restrict__ csrc,
                      __bf16* __restrict__ accG, int fstride, int estride, int nrr,
                      int writeMode) {
  int t = threadIdx.x;
  int l = t & 63;
  int d = blockIdx.x * 4 + (t >> 6);
  int h = l >> 3;
  float res[8] = {0.f, 0.f, 0.f, 0.f, 0.f, 0.f, 0.f, 0.f};
  bool touched = false;
  for (int rr = 0; rr < nrr; rr++) {
    int cnt = deg[rr * NNODES + d];
    if (cnt <= 0) continue;
    touched = true;
    int start = ptrf[rr * NNODES + d];
    if (start < 0) start = 0;
    if (start > NREL * NEDGE) start = NREL * NEDGE;
    if (cnt > NREL * NEDGE - start) cnt = NREL * NEDGE - start;
    int eoff = rr * NH + h;
    int coff = rr * FDIM + l * 8;
    float erh = (float)er[d * estride + eoff];
    float a[8] = {0.f, 0.f, 0.f, 0.f, 0.f, 0.f, 0.f, 0.f};
    float den = 0.f;
    for (int j = 0; j < cnt; j++) {
      int s = csrc[start + j];
      if ((unsigned)s >= (unsigned)NNODES) s = 0;
      float e = (float)el[s * estride + eoff] + erh;
      e = (e > 0.f) ? e : 0.2f * e;
      float ex = __expf(e);
      den += ex;
      bf16x8 fv = *(const bf16x8*)(f + (size_t)s * fstride + coff);
#pragma unroll
      for (int i = 0; i < 8; i++) a[i] += ex * (float)fv[i];
    }
    float inv = 1.f / (den + 1e-9f);
#pragma unroll
    for (int i = 0; i < 8; i++) res[i] += eluf(a[i] * inv);
  }
  if (!touched && !writeMode) return;
  __bf16* ap = accG + (size_t)d * FDIM + l * 8;
  bf16x8 o;
  if (writeMode) {
#pragma unroll
    for (int i = 0; i < 8; i++) o[i] = (__bf16)res[i];
  } else {
    bf16x8 cv = *(bf16x8*)ap;
#pragma unroll
    for (int i = 0; i < 8; i++) o[i] = (__bf16)((float)cv[i] + res[i]);
  }
  *(bf16x8*)ap = o;
}

// ---- layer-2 agg with FUSED head-mean: writes out[N,64] f32 directly ----
__global__ void k_aggm(const __bf16* __restrict__ f, const __bf16* __restrict__ el,
                       const __bf16* __restrict__ er, const int* __restrict__ ptrf,
                       const int* __restrict__ deg, const int* __restrict__ csrc,
                       float* __restrict__ out, int fstride, int estride, int nrr,
                       int writeMode) {
  int t = threadIdx.x;
  int l = t & 63;
  int d = blockIdx.x * 4 + (t >> 6);
  int h = l >> 3;
  float res[8] = {0.f, 0.f, 0.f, 0.f, 0.f, 0.f, 0.f, 0.f};
  for (int rr = 0; rr < nrr; rr++) {
    int cnt = deg[rr * NNODES + d];
    if (cnt <= 0) continue;
    int start = ptrf[rr * NNODES + d];
    if (start < 0) start = 0;
    if (start > NREL * NEDGE) start = NREL * NEDGE;
    if (cnt > NREL * NEDGE - start) cnt = NREL * NEDGE - start;
    int eoff = rr * NH + h;
    int coff = rr * FDIM + l * 8;
    float erh = (float)er[d * estride + eoff];
    float a[8] = {0.f, 0.f, 0.f, 0.f, 0.f, 0.f, 0.f, 0.f};
    float den = 0.f;
    for (int j = 0; j < cnt; j++) {
      int s = csrc[start + j];
      if ((unsigned)s >= (unsigned)NNODES) s = 0;
      float e = (float)el[s * estride + eoff] + erh;
      e = (e > 0.f) ? e : 0.2f * e;
      float ex = __expf(e);
      den += ex;
      bf16x8 fv = *(const bf16x8*)(f + (size_t)s * fstride + coff);
#pragma unroll
      for (int i = 0; i < 8; i++) a[i] += ex * (float)fv[i];
    }
    float inv = 1.f / (den + 1e-9f);
#pragma unroll
    for (int i = 0; i < 8; i++) res[i] += eluf(a[i] * inv);
  }
  // cross-head sum: lanes with same (l&7) across the 8 head-groups
#pragma unroll
  for (int i = 0; i < 8; i++) {
    res[i] += __shfl_xor(res[i], 8);
    res[i] += __shfl_xor(res[i], 16);
    res[i] += __shfl_xor(res[i], 32);
  }
  if (l < 8) {
    float* op = out + (size_t)d * 64 + l * 8;
    f4 v0 = {res[0] * 0.125f, res[1] * 0.125f, res[2] * 0.125f, res[3] * 0.125f};
    f4 v1 = {res[4] * 0.125f, res[5] * 0.125f, res[6] * 0.125f, res[7] * 0.125f};
    if (writeMode) {
      ((f4*)op)[0] = v0;
      ((f4*)op)[1] = v1;
    } else {
      ((f4*)op)[0] += v0;
      ((f4*)op)[1] += v1;
    }
  }
}

// ---- host ----
extern "C" void kernel_launch(void* const* d_in, const int* in_sizes, int n_in,
                              void* d_out, int out_size, void* d_ws, size_t ws_size,
                              hipStream_t stream) {
  const float* x = (const float*)d_in[0];
  const int* srcp = (const int*)d_in[1];
  const int* dstp = (const int*)d_in[2];
  const float* Wl[3]  = {(const float*)d_in[3], (const float*)d_in[6], (const float*)d_in[9]};
  const float* alp[3] = {(const float*)d_in[4], (const float*)d_in[7], (const float*)d_in[10]};
  const float* arl[3] = {(const float*)d_in[5], (const float*)d_in[8], (const float*)d_in[11]};
  float* out = (float*)d_out;
  (void)in_sizes; (void)n_in; (void)out_size;

  auto rup = [](size_t b) { return (b + 255) & ~(size_t)255; };
  // common: b0,b1 [N,512]bf16; deg/ptrf; csrc.  cur+bsum alias into fbuf.
  size_t fixed = 2 * rup((size_t)NNODES * FDIM * 2) +
                 2 * rup((size_t)NREL * NNODES * 4) +
                 rup((size_t)NREL * NEDGE * 4);
  size_t need2 = fixed + rup((size_t)NNODES * 1024 * 2) + 2 * rup((size_t)NNODES * 16 * 2) +
                 rup((size_t)2 * FDIM * FDIM * 2);
  size_t need1 = fixed + rup((size_t)NNODES * 512 * 2) + 2 * rup((size_t)NNODES * 8 * 2) +
                 rup((size_t)FDIM * FDIM * 2);
  int nb;
  if (ws_size >= need2) nb = 2;
  else if (ws_size >= need1) nb = 1;
  else return;

  int nnbsh = (nb == 2) ? 2 : 1;
  int NDIM = 256 << nnbsh;   // fbuf width: 1024 or 512
  int nheads = 4 << nnbsh;   // 16 or 8

  char* ws = (char*)d_ws;
  size_t off = 0;
  auto alloc = [&](size_t bytes) -> void* { void* p = ws + off; off += rup(bytes); return p; };
  __bf16* b0   = (__bf16*)alloc((size_t)NNODES * FDIM * 2);
  __bf16* b1   = (__bf16*)alloc((size_t)NNODES * FDIM * 2);
  __bf16* fbuf = (__bf16*)alloc((size_t)NNODES * NDIM * 2);
  __bf16* el   = (__bf16*)alloc((size_t)NNODES * nheads * 2);
  __bf16* er   = (__bf16*)alloc((size_t)NNODES * nheads * 2);
  __bf16* Wt   = (__bf16*)alloc((size_t)nb * FDIM * FDIM * 2);
  int* deg  = (int*)alloc((size_t)NREL * NNODES * 4);
  int* ptrf = (int*)alloc((size_t)NREL * NNODES * 4);
  int* csrc = (int*)alloc((size_t)NREL * NEDGE * 4);
  // cur + bsum alias into fbuf (dead during CSR build)
  int* cur  = (int*)fbuf;
  int* bsum = (int*)((char*)fbuf + rup((size_t)NREL * NNODES * 4));

  // ---- CSR by dst ----
  hipMemsetAsync(deg, 0, (size_t)NREL * NNODES * 4, stream);
  hipMemsetAsync(cur, 0, (size_t)NREL * NNODES * 4, stream);
  k_count<<<dim3((NEDGE + 255) / 256, NREL), 256, 0, stream>>>(dstp, deg);
  int ntot = NREL * NNODES;
  int nb1 = (ntot + 1023) / 1024;
  k_scan_a<<<nb1, 256, 0, stream>>>(deg, ptrf, bsum, ntot);
  k_scan_b<<<1, 256, 0, stream>>>(bsum, nb1);
  k_scan_c<<<(ntot + 255) / 256, 256, 0, stream>>>(ptrf, bsum, ntot);
  k_scatter<<<dim3((NEDGE + 255) / 256, NREL), 256, 0, stream>>>(srcp, dstp, ptrf, cur, csrc);

  // layer-0 input: conv x -> b1 as [N,256] bf16
  k_conv<<<(NNODES * 256) / 1024, 256, 0, stream>>>(x, b1);

  int ngrid = NMB << nnbsh;  // 3128 (pair) or 1564 (single)
  for (int L = 0; L < 3; L++) {
    int K = (L == 0) ? 256 : FDIM;
    const __bf16* inb = (L == 1) ? b0 : b1;  // L0:b1(x), L1:b0, L2:b1
    __bf16* outb = (L == 0) ? b0 : b1;       // L2 writes d_out instead
    for (int g = 0; g < NREL / nb; g++) {
      k_transW<<<dim3(K / 32, 16, nb), dim3(32, 8), 0, stream>>>(
          Wl[L] + (size_t)g * nb * K * FDIM, Wt, K);
      k_gemm<<<ngrid, 256, 0, stream>>>(inb, Wt, fbuf,
                                        alp[L] + (size_t)g * nb * 512,
                                        arl[L] + (size_t)g * nb * 512,
                                        el, er, NNODES, K, nnbsh);
      if (L < 2)
        k_agg<<<NNODES / 4, 256, 0, stream>>>(fbuf, el, er, ptrf + (size_t)g * nb * NNODES,
                                              deg + (size_t)g * nb * NNODES, csrc, outb,
                                              NDIM, nheads, nb, g == 0 ? 1 : 0);
      else
        k_aggm<<<NNODES / 4, 256, 0, stream>>>(fbuf, el, er, ptrf + (size_t)g * nb * NNODES,
                                               deg + (size_t)g * nb * NNODES, csrc, out,
                                               NDIM, nheads, nb, g == 0 ? 1 : 0);
    }
  }
}